// Round 1
// baseline (5629.757 us; speedup 1.0000x reference)
//
#include <hip/hip_runtime.h>

#define EPS_BN 1e-5f
#define C 128
#define CG 32  // float4 groups per 128-channel row

// ---------------- init: zero BN accumulators, deg = 1 (self loop) -------------
__global__ void k_init(float* __restrict__ sums, int* __restrict__ deg, int n) {
  int i = blockIdx.x * blockDim.x + threadIdx.x;
  if (i < 256) sums[i] = 0.0f;
  if (i < n) deg[i] = 1;
}

// ---------------- column sum / sumsq over rows --------------------------------
__global__ void k_stats(const float4* __restrict__ x4, float* __restrict__ sums, int n) {
  __shared__ float4 s_s[256];
  __shared__ float4 s_q[256];
  int t = threadIdx.x;
  int cg = t & 31;   // channel group (4 channels)
  int rl = t >> 5;   // row lane 0..7
  float4 s = make_float4(0.f, 0.f, 0.f, 0.f);
  float4 q = make_float4(0.f, 0.f, 0.f, 0.f);
  for (int r = blockIdx.x * 8 + rl; r < n; r += gridDim.x * 8) {
    float4 v = x4[(size_t)r * CG + cg];
    s.x += v.x; s.y += v.y; s.z += v.z; s.w += v.w;
    q.x += v.x * v.x; q.y += v.y * v.y; q.z += v.z * v.z; q.w += v.w * v.w;
  }
  s_s[t] = s; s_q[t] = q;
  __syncthreads();
  if (t < 32) {
    for (int j = 1; j < 8; ++j) {
      float4 a = s_s[t + 32 * j];
      float4 b = s_q[t + 32 * j];
      s.x += a.x; s.y += a.y; s.z += a.z; s.w += a.w;
      q.x += b.x; q.y += b.y; q.z += b.z; q.w += b.w;
    }
    atomicAdd(&sums[t * 4 + 0], s.x);
    atomicAdd(&sums[t * 4 + 1], s.y);
    atomicAdd(&sums[t * 4 + 2], s.z);
    atomicAdd(&sums[t * 4 + 3], s.w);
    atomicAdd(&sums[C + t * 4 + 0], q.x);
    atomicAdd(&sums[C + t * 4 + 1], q.y);
    atomicAdd(&sums[C + t * 4 + 2], q.z);
    atomicAdd(&sums[C + t * 4 + 3], q.w);
  }
}

// ---------------- fold BN into per-channel scale/shift ------------------------
__global__ void k_finalize(const float* __restrict__ sums,
                           const float* __restrict__ gamma,
                           const float* __restrict__ beta,
                           float* __restrict__ scale, float* __restrict__ shift,
                           int n) {
  int c = threadIdx.x;
  if (c < C) {
    float inv_n = 1.0f / (float)n;
    float mean = sums[c] * inv_n;
    float var = sums[C + c] * inv_n - mean * mean;
    float rstd = rsqrtf(var + EPS_BN);
    float sc = gamma[c] * rstd;
    scale[c] = sc;
    shift[c] = beta[c] - mean * sc;
  }
}

// ---------------- in-degree (+1 self loop already in init) --------------------
__global__ void k_deg(const int* __restrict__ col, int* __restrict__ deg, int E) {
  int e = blockIdx.x * blockDim.x + threadIdx.x;
  if (e < E) atomicAdd(&deg[col[e]], 1);
}

__global__ void k_dis(const int* __restrict__ deg, float* __restrict__ dis, int n) {
  int i = blockIdx.x * blockDim.x + threadIdx.x;
  if (i < n) dis[i] = rsqrtf((float)deg[i]);
}

// ---------------- edge scatter: out[col] += xn[row] * dis[row]*dis[col] -------
__global__ void k_scatter(const float4* __restrict__ x4,
                          const int* __restrict__ row, const int* __restrict__ col,
                          const float* __restrict__ dis,
                          const float4* __restrict__ scale4,
                          const float4* __restrict__ shift4,
                          float* __restrict__ out, int E) {
  int idx = blockIdx.x * blockDim.x + threadIdx.x;
  int e = idx >> 5;
  if (e >= E) return;
  int g = idx & 31;
  int r = row[e];
  int c = col[e];
  float nrm = dis[r] * dis[c];
  float4 v = x4[(size_t)r * CG + g];
  float4 sc = scale4[g];
  float4 sh = shift4[g];
  float o0 = (v.x * sc.x + sh.x) * nrm;
  float o1 = (v.y * sc.y + sh.y) * nrm;
  float o2 = (v.z * sc.z + sh.z) * nrm;
  float o3 = (v.w * sc.w + sh.w) * nrm;
  float* dst = out + (size_t)c * C + g * 4;
  atomicAdd(dst + 0, o0);
  atomicAdd(dst + 1, o1);
  atomicAdd(dst + 2, o2);
  atomicAdd(dst + 3, o3);
}

// ---------------- in-place GEMM: out = relu((g + xn*invdeg) @ W + b) ----------
__global__ __launch_bounds__(256) void k_gemm(float* __restrict__ out,
                        const float4* __restrict__ x4,
                        const float* __restrict__ W,
                        const float* __restrict__ bias,
                        const float* __restrict__ scale,
                        const float* __restrict__ shift,
                        const float* __restrict__ dis, int n) {
  __shared__ float sW[64 * C];   // 32 KB (one K-chunk of W)
  __shared__ float sG[32 * C];   // 16 KB (32-row tile of g = S*xn)
  int t = threadIdx.x;
  int rowBase = blockIdx.x * 32;

  const float4* scale4 = (const float4*)scale;
  const float4* shift4 = (const float4*)shift;
  float4* sG4 = (float4*)sG;
  float4* sW4 = (float4*)sW;
  const float4* W4 = (const float4*)W;
  const float4* out4 = (const float4*)out;

  // load g tile, folding self-loop contribution xn[i] * (1/deg[i])
  for (int i = t; i < 32 * CG; i += 256) {
    int r = i >> 5, g = i & 31;
    int rw = rowBase + r;
    float4 acc = make_float4(0.f, 0.f, 0.f, 0.f);
    if (rw < n) {
      acc = out4[(size_t)rw * CG + g];
      float4 xv = x4[(size_t)rw * CG + g];
      float d = dis[rw];
      float inv = d * d;
      float4 sc = scale4[g];
      float4 sh = shift4[g];
      acc.x += (xv.x * sc.x + sh.x) * inv;
      acc.y += (xv.y * sc.y + sh.y) * inv;
      acc.z += (xv.z * sc.z + sh.z) * inv;
      acc.w += (xv.w * sc.w + sh.w) * inv;
    }
    sG4[i] = acc;
  }

  int tx = t & 127;  // output col
  int ty = t >> 7;   // 0..1
  float acc[16];
#pragma unroll
  for (int i = 0; i < 16; ++i) acc[i] = 0.f;

  for (int kc = 0; kc < 2; ++kc) {
    // load W chunk rows [kc*64, kc*64+64)
    for (int i = t; i < 64 * C / 4; i += 256) sW4[i] = W4[kc * 2048 + i];
    __syncthreads();
#pragma unroll 4
    for (int k = 0; k < 64; ++k) {
      float w = sW[k * C + tx];
#pragma unroll
      for (int rr = 0; rr < 16; ++rr)
        acc[rr] += sG[(rr * 2 + ty) * C + kc * 64 + k] * w;
    }
    __syncthreads();
  }

  float bv = bias[tx];
#pragma unroll
  for (int rr = 0; rr < 16; ++rr) {
    int rw = rowBase + rr * 2 + ty;
    if (rw < n) {
      float o = acc[rr] + bv;
      out[(size_t)rw * C + tx] = o > 0.f ? o : 0.f;
    }
  }
}

extern "C" void kernel_launch(void* const* d_in, const int* in_sizes, int n_in,
                              void* d_out, int out_size, void* d_ws, size_t ws_size,
                              hipStream_t stream) {
  const float* x = (const float*)d_in[0];
  const int* edge = (const int*)d_in[1];
  const float* gamma = (const float*)d_in[2];
  const float* beta = (const float*)d_in[3];
  const float* W = (const float*)d_in[4];
  const float* bias = (const float*)d_in[5];
  float* out = (float*)d_out;

  int n = in_sizes[0] / C;
  int E = in_sizes[1] / 2;

  float* ws = (float*)d_ws;
  float* sums = ws;              // 256 floats (sum | sumsq)
  float* scale = ws + 256;       // 128
  float* shift = ws + 384;       // 128
  int* deg = (int*)(ws + 512);   // n ints
  float* dis = ws + 512 + n;     // n floats

  hipMemsetAsync(d_out, 0, (size_t)out_size * sizeof(float), stream);
  k_init<<<(n + 255) / 256, 256, 0, stream>>>(sums, deg, n);
  k_stats<<<256, 256, 0, stream>>>((const float4*)x, sums, n);
  k_finalize<<<1, 128, 0, stream>>>(sums, gamma, beta, scale, shift, n);
  k_deg<<<(E + 255) / 256, 256, 0, stream>>>(edge + E, deg, E);
  k_dis<<<(n + 255) / 256, 256, 0, stream>>>(deg, dis, n);
  int totScatter = E * 32;
  k_scatter<<<(totScatter + 255) / 256, 256, 0, stream>>>(
      (const float4*)x, edge, edge + E, dis,
      (const float4*)scale, (const float4*)shift, out, E);
  k_gemm<<<(n + 31) / 32, 256, 0, stream>>>(out, (const float4*)x, W, bias,
                                            scale, shift, dis, n);
}

// Round 2
// 792.403 us; speedup vs baseline: 7.1047x; 7.1047x over previous
//
#include <hip/hip_runtime.h>

#define EPS_BN 1e-5f
#define C 128
#define CG 32  // float4 groups per 128-channel row

// ---------------- init: zero BN accumulators + indeg --------------------------
__global__ void k_init(float* __restrict__ sums, int* __restrict__ indeg, int n) {
  int i = blockIdx.x * blockDim.x + threadIdx.x;
  if (i < 256) sums[i] = 0.0f;
  if (i < n) indeg[i] = 0;
}

// ---------------- column sum / sumsq over rows --------------------------------
__global__ void k_stats(const float4* __restrict__ x4, float* __restrict__ sums, int n) {
  __shared__ float4 s_s[256];
  __shared__ float4 s_q[256];
  int t = threadIdx.x;
  int cg = t & 31;
  int rl = t >> 5;
  float4 s = make_float4(0.f, 0.f, 0.f, 0.f);
  float4 q = make_float4(0.f, 0.f, 0.f, 0.f);
  for (int r = blockIdx.x * 8 + rl; r < n; r += gridDim.x * 8) {
    float4 v = x4[(size_t)r * CG + cg];
    s.x += v.x; s.y += v.y; s.z += v.z; s.w += v.w;
    q.x += v.x * v.x; q.y += v.y * v.y; q.z += v.z * v.z; q.w += v.w * v.w;
  }
  s_s[t] = s; s_q[t] = q;
  __syncthreads();
  if (t < 32) {
    for (int j = 1; j < 8; ++j) {
      float4 a = s_s[t + 32 * j];
      float4 b = s_q[t + 32 * j];
      s.x += a.x; s.y += a.y; s.z += a.z; s.w += a.w;
      q.x += b.x; q.y += b.y; q.z += b.z; q.w += b.w;
    }
    atomicAdd(&sums[t * 4 + 0], s.x);
    atomicAdd(&sums[t * 4 + 1], s.y);
    atomicAdd(&sums[t * 4 + 2], s.z);
    atomicAdd(&sums[t * 4 + 3], s.w);
    atomicAdd(&sums[C + t * 4 + 0], q.x);
    atomicAdd(&sums[C + t * 4 + 1], q.y);
    atomicAdd(&sums[C + t * 4 + 2], q.z);
    atomicAdd(&sums[C + t * 4 + 3], q.w);
  }
}

// ---------------- fold BN into per-channel scale/shift ------------------------
__global__ void k_finalize(const float* __restrict__ sums,
                           const float* __restrict__ gamma,
                           const float* __restrict__ beta,
                           float* __restrict__ scale, float* __restrict__ shift,
                           int n) {
  int c = threadIdx.x;
  if (c < C) {
    float inv_n = 1.0f / (float)n;
    float mean = sums[c] * inv_n;
    float var = sums[C + c] * inv_n - mean * mean;
    float rstd = rsqrtf(var + EPS_BN);
    float sc = gamma[c] * rstd;
    scale[c] = sc;
    shift[c] = beta[c] - mean * sc;
  }
}

// ---------------- in-degree count (dst side, excl self-loop) ------------------
__global__ void k_count(const int* __restrict__ col, int* __restrict__ indeg, int E) {
  int e = blockIdx.x * blockDim.x + threadIdx.x;
  if (e < E) atomicAdd(&indeg[col[e]], 1);
}

__global__ void k_dis(const int* __restrict__ indeg, float* __restrict__ dis, int n) {
  int i = blockIdx.x * blockDim.x + threadIdx.x;
  if (i < n) dis[i] = rsqrtf((float)(indeg[i] + 1));  // +1 self loop
}

// ---------------- 3-kernel exclusive scan of indeg -> offs --------------------
__global__ void k_scan1(const int* __restrict__ indeg, int* __restrict__ offs,
                        int* __restrict__ bsum, int n) {
  __shared__ int sh[256];
  int t = threadIdx.x;
  int i = blockIdx.x * 256 + t;
  int v = (i < n) ? indeg[i] : 0;
  sh[t] = v;
  __syncthreads();
  for (int off = 1; off < 256; off <<= 1) {
    int a = (t >= off) ? sh[t - off] : 0;
    __syncthreads();
    sh[t] += a;
    __syncthreads();
  }
  if (i < n) offs[i] = sh[t] - v;  // exclusive (block-local)
  if (t == 255) bsum[blockIdx.x] = sh[t];
}

__global__ void k_scan2(int* __restrict__ bsum, int nb) {
  __shared__ int sh[1024];
  int t = threadIdx.x;
  int v = (t < nb) ? bsum[t] : 0;
  sh[t] = v;
  __syncthreads();
  for (int off = 1; off < 1024; off <<= 1) {
    int a = (t >= off) ? sh[t - off] : 0;
    __syncthreads();
    sh[t] += a;
    __syncthreads();
  }
  if (t < nb) bsum[t] = sh[t] - v;  // exclusive
}

__global__ void k_scan3(int* __restrict__ offs, int* __restrict__ cursor,
                        const int* __restrict__ bsum, int n, int E) {
  int i = blockIdx.x * blockDim.x + threadIdx.x;
  if (i < n) {
    int o = offs[i] + bsum[i >> 8];
    offs[i] = o;
    cursor[i] = o;
  }
  if (i == 0) offs[n] = E;
}

// ---------------- fill CSR: csr[pos] = row, bucketed by col -------------------
__global__ void k_fill(const int* __restrict__ row, const int* __restrict__ col,
                       int* __restrict__ cursor, int* __restrict__ csr, int E) {
  int e = blockIdx.x * blockDim.x + threadIdx.x;
  if (e < E) {
    int c = col[e];
    int pos = atomicAdd(&cursor[c], 1);
    csr[pos] = row[e];
  }
}

// ---------------- gather-reduce: one wave per dst node ------------------------
// out[c] = dis[c] * ( scale * sum_e x[r_e]*dis[r_e]  +  shift * sum_e dis[r_e] )
__global__ __launch_bounds__(256) void k_gather(
    const float2* __restrict__ x2, const int* __restrict__ csr,
    const int* __restrict__ offs, const float* __restrict__ dis,
    const float2* __restrict__ scale2, const float2* __restrict__ shift2,
    float2* __restrict__ out2, int n) {
  int wid = (blockIdx.x * blockDim.x + threadIdx.x) >> 6;
  int lane = threadIdx.x & 63;
  if (wid >= n) return;
  int s = offs[wid];
  int t = offs[wid + 1];
  float2 acc0 = make_float2(0.f, 0.f), acc1 = make_float2(0.f, 0.f);
  float sd0 = 0.f, sd1 = 0.f;
  int e = s;
  for (; e + 1 < t; e += 2) {
    int r0 = csr[e];
    int r1 = csr[e + 1];
    float d0 = dis[r0];
    float d1 = dis[r1];
    float2 v0 = x2[(size_t)r0 * 64 + lane];
    float2 v1 = x2[(size_t)r1 * 64 + lane];
    acc0.x += v0.x * d0; acc0.y += v0.y * d0; sd0 += d0;
    acc1.x += v1.x * d1; acc1.y += v1.y * d1; sd1 += d1;
  }
  if (e < t) {
    int r = csr[e];
    float d = dis[r];
    float2 v = x2[(size_t)r * 64 + lane];
    acc0.x += v.x * d; acc0.y += v.y * d; sd0 += d;
  }
  acc0.x += acc1.x; acc0.y += acc1.y;
  float sd = sd0 + sd1;
  float dc = dis[wid];
  float2 sc = scale2[lane];
  float2 sh = shift2[lane];
  float2 o;
  o.x = dc * (acc0.x * sc.x + sd * sh.x);
  o.y = dc * (acc0.y * sc.y + sd * sh.y);
  out2[(size_t)wid * 64 + lane] = o;
}

// ---------------- in-place GEMM: out = relu((g + xn*invdeg) @ W + b) ----------
__global__ __launch_bounds__(256) void k_gemm(float* __restrict__ out,
                        const float4* __restrict__ x4,
                        const float* __restrict__ W,
                        const float* __restrict__ bias,
                        const float* __restrict__ scale,
                        const float* __restrict__ shift,
                        const float* __restrict__ dis, int n) {
  __shared__ float sW[64 * C];   // 32 KB
  __shared__ float sG[32 * C];   // 16 KB
  int t = threadIdx.x;
  int rowBase = blockIdx.x * 32;

  const float4* scale4 = (const float4*)scale;
  const float4* shift4 = (const float4*)shift;
  float4* sG4 = (float4*)sG;
  float4* sW4 = (float4*)sW;
  const float4* W4 = (const float4*)W;
  const float4* out4 = (const float4*)out;

  for (int i = t; i < 32 * CG; i += 256) {
    int r = i >> 5, g = i & 31;
    int rw = rowBase + r;
    float4 acc = make_float4(0.f, 0.f, 0.f, 0.f);
    if (rw < n) {
      acc = out4[(size_t)rw * CG + g];
      float4 xv = x4[(size_t)rw * CG + g];
      float d = dis[rw];
      float inv = d * d;
      float4 sc = scale4[g];
      float4 sh = shift4[g];
      acc.x += (xv.x * sc.x + sh.x) * inv;
      acc.y += (xv.y * sc.y + sh.y) * inv;
      acc.z += (xv.z * sc.z + sh.z) * inv;
      acc.w += (xv.w * sc.w + sh.w) * inv;
    }
    sG4[i] = acc;
  }

  int tx = t & 127;
  int ty = t >> 7;
  float acc[16];
#pragma unroll
  for (int i = 0; i < 16; ++i) acc[i] = 0.f;

  for (int kc = 0; kc < 2; ++kc) {
    for (int i = t; i < 64 * C / 4; i += 256) sW4[i] = W4[kc * 2048 + i];
    __syncthreads();
#pragma unroll 4
    for (int k = 0; k < 64; ++k) {
      float w = sW[k * C + tx];
#pragma unroll
      for (int rr = 0; rr < 16; ++rr)
        acc[rr] += sG[(rr * 2 + ty) * C + kc * 64 + k] * w;
    }
    __syncthreads();
  }

  float bv = bias[tx];
#pragma unroll
  for (int rr = 0; rr < 16; ++rr) {
    int rw = rowBase + rr * 2 + ty;
    if (rw < n) {
      float o = acc[rr] + bv;
      out[(size_t)rw * C + tx] = o > 0.f ? o : 0.f;
    }
  }
}

extern "C" void kernel_launch(void* const* d_in, const int* in_sizes, int n_in,
                              void* d_out, int out_size, void* d_ws, size_t ws_size,
                              hipStream_t stream) {
  const float* x = (const float*)d_in[0];
  const int* edge = (const int*)d_in[1];
  const float* gamma = (const float*)d_in[2];
  const float* beta = (const float*)d_in[3];
  const float* W = (const float*)d_in[4];
  const float* bias = (const float*)d_in[5];
  float* out = (float*)d_out;

  int n = in_sizes[0] / C;
  int E = in_sizes[1] / 2;
  int nb = (n + 255) / 256;  // scan blocks (must be <= 1024)

  float* ws = (float*)d_ws;
  float* sums = ws;                    // 256 f
  float* scale = ws + 256;             // 128 f
  float* shift = ws + 384;             // 128 f
  float* dis = ws + 512;               // n f
  int* indeg = (int*)(ws + 512 + n);   // n i
  int* offs = indeg + n;               // n+1 i
  int* cursor = offs + n + 1;          // n i
  int* bsum = cursor + n;              // 1024 i
  int* csr = bsum + 1024;              // E i

  k_init<<<(n + 255) / 256, 256, 0, stream>>>(sums, indeg, n);
  k_stats<<<256, 256, 0, stream>>>((const float4*)x, sums, n);
  k_finalize<<<1, 128, 0, stream>>>(sums, gamma, beta, scale, shift, n);
  k_count<<<(E + 255) / 256, 256, 0, stream>>>(edge + E, indeg, E);
  k_dis<<<(n + 255) / 256, 256, 0, stream>>>(indeg, dis, n);
  k_scan1<<<nb, 256, 0, stream>>>(indeg, offs, bsum, n);
  k_scan2<<<1, 1024, 0, stream>>>(bsum, nb);
  k_scan3<<<(n + 255) / 256, 256, 0, stream>>>(offs, cursor, bsum, n, E);
  k_fill<<<(E + 255) / 256, 256, 0, stream>>>(edge, edge + E, cursor, csr, E);
  k_gather<<<(n * 64 + 255) / 256, 256, 0, stream>>>(
      (const float2*)x, csr, offs, dis, (const float2*)scale,
      (const float2*)shift, (float2*)out, n);
  k_gemm<<<(n + 31) / 32, 256, 0, stream>>>(out, (const float4*)x, W, bias,
                                            scale, shift, dis, n);
}